// Round 6
// baseline (410.002 us; speedup 1.0000x reference)
//
#include <hip/hip_runtime.h>

typedef unsigned short u16;
typedef unsigned int u32;
typedef __bf16 bf16x8 __attribute__((ext_vector_type(8)));
typedef float f32x4 __attribute__((ext_vector_type(4)));

#define AS1 __attribute__((address_space(1)))
#define AS3 __attribute__((address_space(3)))

// ---- fp32 -> bf16 (RNE) ----
__device__ inline u16 f2bf(float f) {
  union { float f; unsigned u; } a; a.f = f;
  unsigned u = a.u;
  return (u16)((u + 0x7fffu + ((u >> 16) & 1u)) >> 16);
}

// ---- flag layout (u32 indices into F) ----
#define F_CUR 0    // work-queue cursor
#define F_CVT 1    // cvt arrivals (target 256)
#define F_QROW 8   // 32: Q row-block proj tiles done (target 4)
#define F_KROW 40  // 32: K row-block proj tiles done (target 4)
#define F_SROW 72  // 32: qkt tiles done per (z,m) (target 2(m+1))
#define F_SMC 104  // 32: softmax slices done per (z,m) (target 16)
#define F_VTC 136  // 16: vt key-tiles done per (z,dim) (target 8)
#define F_PVC 152  // 32: pv chunks done per (z,m)
#define NITEMS 1632

__device__ __forceinline__ void gate1(u32* f, u32 tgt, int tid) {
  if (tid == 0) {
    while (__hip_atomic_load(f, __ATOMIC_ACQUIRE, __HIP_MEMORY_SCOPE_AGENT) < tgt)
      __builtin_amdgcn_s_sleep(2);
  }
  __syncthreads();
}
__device__ __forceinline__ void post1(u32* f, int tid) {
  __syncthreads();                 // all threads' stores drained (vmcnt0 before barrier)
  if (tid == 0) {
    __threadfence();               // device-scope writeback
    __hip_atomic_fetch_add(f, 1u, __ATOMIC_RELEASE, __HIP_MEMORY_SCOPE_AGENT);
  }
}

// ============================================================================
// 256xBN 8-wave GEMM core, 4-phase dead-region schedule: C = A @ B^T.
//   BN=256: wave tile 128x64, 16 MFMA/phase; BN=128: wave tile 128x32, 8/phase.
//   RAW s_barrier only; counted vmcnt(BSW) per K-tile (never drains queue).
//   T2 swizzle: 16B slot ^= (row&7) on both staged source and ds_read.
// ============================================================================
template <typename CT, int BN>
__device__ __forceinline__ void gemm_core(
    u16* __restrict__ lds,
    const u16* __restrict__ A, const u16* __restrict__ B, CT* __restrict__ C,
    int nt, int lda, int ldb, int ldc, int m0, int n0) {
  constexpr int ABUF = 16384;      // 256 rows x 64 u16 per A buffer
  constexpr int BBUF = BN * 64;
  constexpr int BSW = BN / 64;     // B staging sweeps per tile (4 or 2)
  constexpr int NI = BN / 64;      // n-frags per wave

  const int tid = threadIdx.x;
  const int ln = tid & 63, wv = tid >> 6;
  const int wr = wv >> 2, wc = wv & 3;  // 2 x 4 wave grid

  auto sweep = [&](const u16* src, int ld, int t, int s, int base) {
    const int c = s * 512 + tid;
    const int row = c >> 3, slot = c & 7;
    const int col = (slot ^ (row & 7)) * 8;
    __builtin_amdgcn_global_load_lds(
        (const AS1 void*)(src + (size_t)row * ld + (size_t)t * 64 + col),
        (AS3 void*)(&lds[base + c * 8]), 16, 0, 0);
  };

  f32x4 acc[8][NI] = {};

  // prologue: tiles 0 and 1 fully staged
#pragma unroll
  for (int s = 0; s < BSW; ++s) sweep(B, ldb, 0, s, 2 * ABUF);
#pragma unroll
  for (int s = 0; s < 4; ++s) sweep(A, lda, 0, s, 0);
  if (nt > 1) {
#pragma unroll
    for (int s = 0; s < BSW; ++s) sweep(B, ldb, 1, s, 2 * ABUF + BBUF);
#pragma unroll
    for (int s = 0; s < 4; ++s) sweep(A, lda, 1, s, ABUF);
    if constexpr (BSW == 4) asm volatile("s_waitcnt vmcnt(8)" ::: "memory");
    else                    asm volatile("s_waitcnt vmcnt(6)" ::: "memory");
  } else {
    asm volatile("s_waitcnt vmcnt(0)" ::: "memory");
  }
  __builtin_amdgcn_s_barrier();

  for (int t = 0; t < nt; ++t) {
    const int p = t & 1;
    const u16* La = &lds[p * ABUF];
    const u16* Lb = &lds[2 * ABUF + p * BBUF];
    bf16x8 bfr[NI][2];
#pragma unroll
    for (int q = 0; q < 4; ++q) {
      if (q == 0) {
        __builtin_amdgcn_sched_barrier(0);  // pin reads below publishing barrier
#pragma unroll
        for (int ni = 0; ni < NI; ++ni)
#pragma unroll
          for (int ks = 0; ks < 2; ++ks) {
            const int row = wc * (BN / 4) + ni * 16 + (ln & 15);
            const int kc = ks * 4 + (ln >> 4);
            bfr[ni][ks] = *(const bf16x8*)&Lb[row * 64 + ((kc ^ (row & 7)) << 3)];
          }
      }
      bf16x8 afr[2][2];
#pragma unroll
      for (int mi = 0; mi < 2; ++mi)
#pragma unroll
        for (int ks = 0; ks < 2; ++ks) {
          const int row = wr * 128 + (q * 2 + mi) * 16 + (ln & 15);
          const int kc = ks * 4 + (ln >> 4);
          afr[mi][ks] = *(const bf16x8*)&La[row * 64 + ((kc ^ (row & 7)) << 3)];
        }
      // dead-region staging
      if (q == 0)      { if (t >= 1 && t + 1 < nt) { sweep(A, lda, t + 1, 0, (p ^ 1) * ABUF); sweep(A, lda, t + 1, 1, (p ^ 1) * ABUF); } }
      else if (q == 1) { if (t >= 1 && t + 1 < nt) { sweep(A, lda, t + 1, 2, (p ^ 1) * ABUF); sweep(A, lda, t + 1, 3, (p ^ 1) * ABUF); } }
      else if (q == 2) { if (t + 2 < nt) { sweep(B, ldb, t + 2, 0, 2 * ABUF + p * BBUF); if (BSW == 4) sweep(B, ldb, t + 2, 1, 2 * ABUF + p * BBUF); } }
      else             { if (t + 2 < nt) { if (BSW == 4) { sweep(B, ldb, t + 2, 2, 2 * ABUF + p * BBUF); sweep(B, ldb, t + 2, 3, 2 * ABUF + p * BBUF); } else { sweep(B, ldb, t + 2, 1, 2 * ABUF + p * BBUF); } } }

      __builtin_amdgcn_s_barrier();
      __builtin_amdgcn_s_setprio(1);
#pragma unroll
      for (int mi = 0; mi < 2; ++mi)
#pragma unroll
        for (int ni = 0; ni < NI; ++ni)
#pragma unroll
          for (int ks = 0; ks < 2; ++ks)
            acc[q * 2 + mi][ni] = __builtin_amdgcn_mfma_f32_16x16x32_bf16(
                afr[mi][ks], bfr[ni][ks], acc[q * 2 + mi][ni], 0, 0, 0);
      __builtin_amdgcn_s_setprio(0);
      if (q == 3) {
        if (t + 2 < nt) {
          if constexpr (BSW == 4) asm volatile("s_waitcnt vmcnt(4)" ::: "memory");
          else                    asm volatile("s_waitcnt vmcnt(2)" ::: "memory");
        } else if (t + 1 < nt) {
          asm volatile("s_waitcnt vmcnt(0)" ::: "memory");
        }
      }
      __builtin_amdgcn_s_barrier();
    }
  }

  // epilogue: D col = lane&15 (n), row = (lane>>4)*4 + reg (m)
#pragma unroll
  for (int mi = 0; mi < 8; ++mi) {
    const int rbase = m0 + wr * 128 + mi * 16 + (ln >> 4) * 4;
#pragma unroll
    for (int ni = 0; ni < NI; ++ni) {
      const int col = n0 + wc * (BN / 4) + ni * 16 + (ln & 15);
#pragma unroll
      for (int r = 0; r < 4; ++r) {
        const float v = acc[mi][ni][r];
        CT* ptr = &C[(size_t)(rbase + r) * ldc + col];
        if constexpr (sizeof(CT) == 4) *(float*)ptr = v;
        else                           *ptr = f2bf(v);
      }
    }
  }
}

// pv chunk classes (desc nt): m-tile, k0 (K-tiles), nt, slot (0=out,1=slot1,2=slot2)
__constant__ signed char CPM[16] = {5,5,7,7,7,6,4,4,6,6,3,3,1,2,2,0};
__constant__ signed char CPK[16] = {0,12,0,11,22,0,0,10,10,19,0,8,0,0,6,0};
__constant__ signed char CPN[16] = {12,12,11,11,10,10,10,10,9,9,8,8,8,6,6,4};
__constant__ signed char CPS[16] = {0,1,0,1,2,0,0,1,1,2,0,1,0,0,1,0};

__global__ __launch_bounds__(512, 2) void mega_kernel(
    const float* __restrict__ x, const float* __restrict__ Wq,
    const float* __restrict__ Wk, const float* __restrict__ Wv,
    u16* __restrict__ xb, u16* __restrict__ wqb, u16* __restrict__ wkb,
    u16* __restrict__ wvb, u16* __restrict__ Qb, u16* __restrict__ Kb,
    u16* __restrict__ VTb, float* __restrict__ Sb, float* __restrict__ out,
    u32* __restrict__ F) {
  __shared__ __align__(16) u16 lds[65536];
  __shared__ int qslot;
  const int tid = threadIdx.x;

  // ---- phase 0: fp32 -> bf16 converts, grid-stride over all 256 blocks ----
  {
    const int gid = blockIdx.x * 512 + tid;
    for (int i = gid; i < 2097152; i += 131072) {   // x: 8192x1024
      float4 v = ((const float4*)x)[i];
      ushort4 o; o.x = f2bf(v.x); o.y = f2bf(v.y); o.z = f2bf(v.z); o.w = f2bf(v.w);
      ((ushort4*)xb)[i] = o;
    }
    for (int i = gid; i < 262144; i += 131072) {    // each W: 1024x1024
      float4 v = ((const float4*)Wq)[i];
      ushort4 o; o.x = f2bf(v.x); o.y = f2bf(v.y); o.z = f2bf(v.z); o.w = f2bf(v.w);
      ((ushort4*)wqb)[i] = o;
      v = ((const float4*)Wk)[i];
      o.x = f2bf(v.x); o.y = f2bf(v.y); o.z = f2bf(v.z); o.w = f2bf(v.w);
      ((ushort4*)wkb)[i] = o;
      v = ((const float4*)Wv)[i];
      o.x = f2bf(v.x); o.y = f2bf(v.y); o.z = f2bf(v.z); o.w = f2bf(v.w);
      ((ushort4*)wvb)[i] = o;
    }
    post1(&F[F_CVT], tid);
  }

  // ---- flagged work queue ----
  for (;;) {
    __syncthreads();
    if (tid == 0)
      qslot = (int)__hip_atomic_fetch_add(&F[F_CUR], 1u, __ATOMIC_RELAXED,
                                          __HIP_MEMORY_SCOPE_AGENT);
    __syncthreads();
    const int it = qslot;
    if (it >= NITEMS) break;

    if (it < 256) {
      // ---- proj: Q = x Wq^T (w=0) / K = x Wk^T (w=1), 256^2 tiles ----
      gate1(&F[F_CVT], 256, tid);
      const int w = it >> 7, r = it & 127;
      const int rb = r >> 2, n0 = (r & 3) * 256;   // rb: global 256-row block 0..31
      const u16* Bm = w ? wkb : wqb;
      u16* Cm = w ? Kb : Qb;
      gemm_core<u16, 256>(lds, xb + (size_t)rb * 256 * 1024, Bm + (size_t)n0 * 1024,
                          Cm, 16, 1024, 1024, 1024, rb * 256, n0);
      post1(&F[(w ? F_KROW : F_QROW) + rb], tid);
    } else if (it < 384) {
      // ---- vt: VT_b = Wv x_b^T, 256^2 tiles ----
      gate1(&F[F_CVT], 256, tid);
      const int j = it - 256;
      const int kt = j >> 4, z = (j >> 2) & 3, mt = j & 3;
      gemm_core<u16, 256>(lds, wvb + (size_t)mt * 256 * 1024,
                          xb + ((size_t)z * 2048 + kt * 256) * 1024,
                          VTb + (size_t)z * 1024 * 2048,
                          16, 1024, 1024, 2048, mt * 256, kt * 256);
      post1(&F[F_VTC + z * 4 + mt], tid);
    } else if (it < 672) {
      // ---- qkt: S tile 256x128, only below-diagonal halves, desc-m order ----
      const int j = it - 384;
      const int p = 71 - (j >> 2), z = j & 3;
      int m = 0;
      while ((m + 1) * (m + 2) <= p) ++m;
      const int h = p - m * (m + 1);               // key half-tile 0..2m+1
      gate1(&F[F_QROW + z * 8 + m], 4, tid);
      gate1(&F[F_KROW + z * 8 + (h >> 1)], 4, tid);
      gemm_core<float, 128>(lds,
          Qb + ((size_t)z * 2048 + m * 256) * 1024,
          Kb + ((size_t)z * 2048 + h * 128) * 1024,
          Sb + (size_t)z * 2048 * 2048,
          16, 1024, 1024, 2048, m * 256, h * 128);
      post1(&F[F_SROW + z * 8 + m], tid);
    } else if (it < 1184) {
      // ---- softmax slice: 16 rows of (z,m), writes bf16 P in place ----
      const int j = it - 672;
      const int m = 7 - (j >> 6), z = (j >> 4) & 3, s = j & 15;
      gate1(&F[F_SROW + z * 8 + m], 2u * (m + 1), tid);
      const int iters = m + 1;                      // float4-iters of 64 lanes
      const int wvid = tid >> 6, lane = tid & 63;
      float* S0 = Sb + (size_t)z * 2048 * 2048;
#pragma unroll 2
      for (int rr = wvid; rr < 16; rr += 8) {
        const int r = m * 256 + s * 16 + rr;
        float* row = S0 + (size_t)r * 2048;
        float vals[8][4];
        float mx = -3.4e38f;
#pragma unroll
        for (int it2 = 0; it2 < 8; ++it2)
          if (it2 < iters) {
            const int idx = it2 * 64 + lane;
            float4 v = ((const float4*)row)[idx];
            const int j0 = idx * 4;
            vals[it2][0] = (j0 <= r) ? v.x * 0.03125f : -3.4e38f;
            vals[it2][1] = (j0 + 1 <= r) ? v.y * 0.03125f : -3.4e38f;
            vals[it2][2] = (j0 + 2 <= r) ? v.z * 0.03125f : -3.4e38f;
            vals[it2][3] = (j0 + 3 <= r) ? v.w * 0.03125f : -3.4e38f;
            mx = fmaxf(mx, fmaxf(fmaxf(vals[it2][0], vals[it2][1]),
                                 fmaxf(vals[it2][2], vals[it2][3])));
          }
#pragma unroll
        for (int o = 32; o; o >>= 1) mx = fmaxf(mx, __shfl_xor(mx, o, 64));
        float sum = 0.f;
#pragma unroll
        for (int it2 = 0; it2 < 8; ++it2)
          if (it2 < iters) {
#pragma unroll
            for (int e = 0; e < 4; ++e) {
              const float pp = __expf(vals[it2][e] - mx);
              vals[it2][e] = pp;
              sum += pp;
            }
          }
#pragma unroll
        for (int o = 32; o; o >>= 1) sum += __shfl_xor(sum, o, 64);
        const float rcp = 1.f / sum;
        u16* prow = (u16*)row;
#pragma unroll
        for (int it2 = 0; it2 < 8; ++it2)
          if (it2 < iters) {
            ushort4 o4;
            o4.x = f2bf(vals[it2][0] * rcp);
            o4.y = f2bf(vals[it2][1] * rcp);
            o4.z = f2bf(vals[it2][2] * rcp);
            o4.w = f2bf(vals[it2][3] * rcp);
            ((ushort4*)prow)[it2 * 64 + lane] = o4;
          }
      }
      post1(&F[F_SMC + z * 8 + m], tid);
    } else if (it < 1440) {
      // ---- pv chunk: O_b = P_b VT_b^T; slots carved from Sb's dead half ----
      const int j = it - 1184;
      const int cls = j >> 4, z = (j >> 2) & 3, n = j & 3;
      const int m = CPM[cls], k0 = CPK[cls], ntc = CPN[cls], sl = CPS[cls];
      gate1(&F[F_SMC + z * 8 + m], 16, tid);
      gate1(&F[F_VTC + z * 4 + n], 8, tid);
      const u16* Ap = (const u16*)(Sb + (size_t)z * 2048 * 2048) +
                      (size_t)m * 256 * 4096 + (size_t)k0 * 64;
      const u16* Bp = VTb + (size_t)z * 1024 * 2048 + (size_t)n * 256 * 2048 +
                      (size_t)k0 * 64;
      float* Cp;
      int ldc;
      if (sl == 0) { Cp = out + (size_t)z * 2048 * 1024; ldc = 1024; }
      else if (sl == 1) { Cp = Sb + (size_t)z * 2048 * 2048 + 1024; ldc = 2048; }            // rows 512..2047 self-region
      else { Cp = Sb + (size_t)z * 2048 * 2048 + 1024 - (size_t)1536 * 2048; ldc = 2048; }   // rows 1536..2047 -> region rows 0..511
      gemm_core<float, 256>(lds, Ap, Bp, Cp, ntc, 4096, 2048, ldc, m * 256, n * 256);
      post1(&F[F_PVC + z * 8 + m], tid);
    } else {
      // ---- reduce: out += slot1 (+slot2 for m>=6), fixed order -> deterministic ----
      const int j = it - 1440;
      const int m = 2 + (j >> 5), z = (j >> 3) & 3, s = j & 7;
      const u32 tgt = (m >= 6) ? 12u : 8u;
      gate1(&F[F_PVC + z * 8 + m], tgt, tid);
      float* ob = out + (size_t)z * 2048 * 1024;
      const float* s1 = Sb + (size_t)z * 2048 * 2048 + 1024;
      const float* s2 = s1 - (size_t)1536 * 2048;
      const int r0 = m * 256 + s * 32;
      for (int k = tid; k < 32 * 256; k += 512) {   // 32 rows x 256 float4
        const int rr = r0 + (k >> 8), cc = k & 255;
        float4 o = ((float4*)(ob + (size_t)rr * 1024))[cc];
        float4 a = ((const float4*)(s1 + (size_t)rr * 2048))[cc];
        o.x += a.x; o.y += a.y; o.z += a.z; o.w += a.w;
        if (m >= 6) {
          float4 b = ((const float4*)(s2 + (size_t)rr * 2048))[cc];
          o.x += b.x; o.y += b.y; o.z += b.z; o.w += b.w;
        }
        ((float4*)(ob + (size_t)rr * 1024))[cc] = o;
      }
    }
  }
}

extern "C" void kernel_launch(void* const* d_in, const int* in_sizes, int n_in,
                              void* d_out, int out_size, void* d_ws, size_t ws_size,
                              hipStream_t stream) {
  const float* x  = (const float*)d_in[0];
  const float* Wq = (const float*)d_in[1];
  const float* Wk = (const float*)d_in[2];
  const float* Wv = (const float*)d_in[3];
  float* out = (float*)d_out;

  char* ws = (char*)d_ws;
  u16* xb   = (u16*)(ws);                        // 16 MB  x bf16 [8192][1024]
  u16* wqb  = (u16*)(ws + (16ul << 20));         //  2 MB
  u16* wkb  = (u16*)(ws + (18ul << 20));         //  2 MB
  u16* wvb  = (u16*)(ws + (20ul << 20));         //  2 MB
  u16* Qb   = (u16*)(ws + (22ul << 20));         // 16 MB  Q bf16 [4][2048][1024]
  u16* Kb   = (u16*)(ws + (38ul << 20));         // 16 MB  K bf16
  u16* VTb  = (u16*)(ws + (54ul << 20));         // 16 MB  V^T bf16 [4][1024][2048]
  float* Sb = (float*)(ws + (70ul << 20));       // 64 MB  scores fp32; P bf16 in cols
                                                 //        0..1023(f32); dead upper half
                                                 //        hosts pv slot1/slot2 scratch
  // flags: just past our 134 MB layout if the workspace allows, else at the tail
  size_t foff = (ws_size >= (134ul << 20) + 4096) ? (134ul << 20)
                                                  : ((ws_size - 4096) & ~(size_t)255);
  u32* F = (u32*)(ws + foff);

  hipMemsetAsync(F, 0, 1024, stream);
  mega_kernel<<<256, 512, 0, stream>>>(x, Wq, Wk, Wv, xb, wqb, wkb, wvb,
                                       Qb, Kb, VTb, Sb, out, F);
}

// Round 7
// 340.415 us; speedup vs baseline: 1.2044x; 1.2044x over previous
//
#include <hip/hip_runtime.h>

typedef unsigned short u16;
typedef unsigned int u32;
typedef __bf16 bf16x8 __attribute__((ext_vector_type(8)));
typedef float f32x4 __attribute__((ext_vector_type(4)));

#define AS1 __attribute__((address_space(1)))
#define AS3 __attribute__((address_space(3)))

// ---- fp32 -> bf16 (RNE) ----
__device__ inline u16 f2bf(float f) {
  union { float f; unsigned u; } a; a.f = f;
  unsigned u = a.u;
  return (u16)((u + 0x7fffu + ((u >> 16) & 1u)) >> 16);
}

// ---- flag layout (u32 indices into F) ----
#define F_C1 0     // D1 work-queue cursor
#define F_C2 1     // D2 work-queue cursor
#define F_CVT 2    // cvt arrivals (target 256)
#define F_PROJ 3   // proj tiles done (target 256)
#define F_QKT 8    // 32: qkt tiles done per (z,m), target m+1
#define F_PVC 40   // 32: pv chunks done per (z,m)
#define N_D1 784   // 256 proj + 144 qkt + 256 vt + 128 sm
#define N_D2 448   // 256 pv + 192 red

__device__ __forceinline__ void gate1(volatile u32* f, u32 tgt, int tid) {
  if (tid == 0) {
    while (__hip_atomic_load((u32*)f, __ATOMIC_ACQUIRE, __HIP_MEMORY_SCOPE_AGENT) < tgt)
      __builtin_amdgcn_s_sleep(2);
  }
  __syncthreads();
}
__device__ __forceinline__ void post1(u32* f, int tid) {
  __syncthreads();                 // all threads' stores drained before flag
  if (tid == 0) {
    __threadfence();               // device-scope writeback
    __hip_atomic_fetch_add(f, 1u, __ATOMIC_RELEASE, __HIP_MEMORY_SCOPE_AGENT);
  }
}

// ============================================================================
// BMx256 8-wave GEMM core, 4-phase dead-region schedule: C = A @ B^T.
//   (verbatim from round 5 — proven correct + fast)
// ============================================================================
template <typename CT, int BM>
__device__ __forceinline__ void gemm_core(
    u16* __restrict__ lds,
    const u16* __restrict__ A, const u16* __restrict__ B, CT* __restrict__ C,
    int nt, int lda, int ldb, int ldc, int m0, int n0) {
  constexpr int ABUF = BM * 64;     // u16 per A buffer
  constexpr int ASW = BM / 64;      // A staging sweeps per tile (4 or 2)
  constexpr int PH_MI = BM / 128;   // m-frags per phase (2 or 1)

  const int tid = threadIdx.x;
  const int ln = tid & 63, wv = tid >> 6;
  const int wr = wv >> 2, wc = wv & 3;  // 2 x 4 wave grid

  auto sweep = [&](const u16* src, int ld, int t, int s, int base) {
    const int c = s * 512 + tid;
    const int row = c >> 3, slot = c & 7;
    const int col = (slot ^ (row & 7)) * 8;
    __builtin_amdgcn_global_load_lds(
        (const AS1 void*)(src + (size_t)row * ld + (size_t)t * 64 + col),
        (AS3 void*)(&lds[base + c * 8]), 16, 0, 0);
  };

  f32x4 acc[2 * BM / 64][4] = {};

  // prologue: tiles 0 and 1 fully staged
#pragma unroll
  for (int s = 0; s < 4; ++s) sweep(B, ldb, 0, s, 2 * ABUF);
#pragma unroll
  for (int s = 0; s < ASW; ++s) sweep(A, lda, 0, s, 0);
  if (nt > 1) {
#pragma unroll
    for (int s = 0; s < 4; ++s) sweep(B, ldb, 1, s, 2 * ABUF + 16384);
#pragma unroll
    for (int s = 0; s < ASW; ++s) sweep(A, lda, 1, s, ABUF);
    if constexpr (ASW == 4) asm volatile("s_waitcnt vmcnt(8)" ::: "memory");
    else                    asm volatile("s_waitcnt vmcnt(6)" ::: "memory");
  } else {
    asm volatile("s_waitcnt vmcnt(0)" ::: "memory");
  }
  __builtin_amdgcn_s_barrier();

  for (int t = 0; t < nt; ++t) {
    const int p = t & 1;
    const u16* La = &lds[p * ABUF];
    const u16* Lb = &lds[2 * ABUF + p * 16384];
    bf16x8 bfr[4][2];
#pragma unroll
    for (int q = 0; q < 4; ++q) {
      if (q == 0) {
        __builtin_amdgcn_sched_barrier(0);  // pin reads below publishing barrier
#pragma unroll
        for (int ni = 0; ni < 4; ++ni)
#pragma unroll
          for (int ks = 0; ks < 2; ++ks) {
            const int row = wc * 64 + ni * 16 + (ln & 15);
            const int kc = ks * 4 + (ln >> 4);
            bfr[ni][ks] = *(const bf16x8*)&Lb[row * 64 + ((kc ^ (row & 7)) << 3)];
          }
      }
      bf16x8 afr[PH_MI][2];
#pragma unroll
      for (int mi = 0; mi < PH_MI; ++mi)
#pragma unroll
        for (int ks = 0; ks < 2; ++ks) {
          const int row = wr * (BM / 2) + (q * PH_MI + mi) * 16 + (ln & 15);
          const int kc = ks * 4 + (ln >> 4);
          afr[mi][ks] = *(const bf16x8*)&La[row * 64 + ((kc ^ (row & 7)) << 3)];
        }
      // dead-region staging (tile 0 skips A(1): staged in prologue)
      if constexpr (PH_MI == 2) {
        if (q == 0)      { if (t >= 1 && t + 1 < nt) { sweep(A, lda, t + 1, 0, (p ^ 1) * ABUF); sweep(A, lda, t + 1, 1, (p ^ 1) * ABUF); } }
        else if (q == 1) { if (t >= 1 && t + 1 < nt) { sweep(A, lda, t + 1, 2, (p ^ 1) * ABUF); sweep(A, lda, t + 1, 3, (p ^ 1) * ABUF); } }
        else if (q == 2) { if (t + 2 < nt) { sweep(B, ldb, t + 2, 0, 2 * ABUF + p * 16384); sweep(B, ldb, t + 2, 1, 2 * ABUF + p * 16384); } }
        else             { if (t + 2 < nt) { sweep(B, ldb, t + 2, 2, 2 * ABUF + p * 16384); sweep(B, ldb, t + 2, 3, 2 * ABUF + p * 16384); } }
      } else {
        if (q == 0)      { if (t >= 1 && t + 1 < nt) { sweep(A, lda, t + 1, 0, (p ^ 1) * ABUF); sweep(A, lda, t + 1, 1, (p ^ 1) * ABUF); } }
        else if (q == 2) { if (t + 2 < nt) { sweep(B, ldb, t + 2, 0, 2 * ABUF + p * 16384); sweep(B, ldb, t + 2, 1, 2 * ABUF + p * 16384); } }
        else if (q == 3) { if (t + 2 < nt) { sweep(B, ldb, t + 2, 2, 2 * ABUF + p * 16384); sweep(B, ldb, t + 2, 3, 2 * ABUF + p * 16384); } }
      }

      __builtin_amdgcn_s_barrier();
      __builtin_amdgcn_s_setprio(1);
#pragma unroll
      for (int mi = 0; mi < PH_MI; ++mi)
#pragma unroll
        for (int ni = 0; ni < 4; ++ni)
#pragma unroll
          for (int ks = 0; ks < 2; ++ks)
            acc[q * PH_MI + mi][ni] = __builtin_amdgcn_mfma_f32_16x16x32_bf16(
                afr[mi][ks], bfr[ni][ks], acc[q * PH_MI + mi][ni], 0, 0, 0);
      __builtin_amdgcn_s_setprio(0);
      if (q == 3) {
        if (t + 2 < nt)      asm volatile("s_waitcnt vmcnt(4)" ::: "memory");
        else if (t + 1 < nt) asm volatile("s_waitcnt vmcnt(0)" ::: "memory");
      }
      __builtin_amdgcn_s_barrier();
    }
  }

  // epilogue: D col = lane&15 (n), row = (lane>>4)*4 + reg (m) — m89-verified
#pragma unroll
  for (int mi = 0; mi < 2 * BM / 64; ++mi) {
    const int rbase = m0 + wr * (BM / 2) + mi * 16 + (ln >> 4) * 4;
#pragma unroll
    for (int ni = 0; ni < 4; ++ni) {
      const int col = n0 + wc * 64 + ni * 16 + (ln & 15);
#pragma unroll
      for (int r = 0; r < 4; ++r) {
        const float v = acc[mi][ni][r];
        CT* ptr = &C[(size_t)(rbase + r) * ldc + col];
        if constexpr (sizeof(CT) == 4) *(float*)ptr = v;
        else                           *ptr = f2bf(v);
      }
    }
  }
}

// ============================================================================
// D1: cvt -> proj(256) -> qkt(144, gate all-proj) -> vt(256) -> sm(128)
// ============================================================================
__global__ __launch_bounds__(512, 2) void fwd_kernel(
    const float* __restrict__ x, const float* __restrict__ Wq,
    const float* __restrict__ Wk, const float* __restrict__ Wv,
    u16* __restrict__ xb, u16* __restrict__ wqb, u16* __restrict__ wkb,
    u16* __restrict__ wvb, u16* __restrict__ Qb, u16* __restrict__ Kb,
    u16* __restrict__ VTb, float* __restrict__ Sb, u32* __restrict__ F) {
  __shared__ __align__(16) u16 lds[65536];
  __shared__ int qs;
  const int tid = threadIdx.x;

  // ---- cvt phase: all 256 blocks grid-stride ----
  {
    const int gid = blockIdx.x * 512 + tid;
    for (int i = gid; i < 2097152; i += 131072) {   // x: 8192x1024
      float4 v = ((const float4*)x)[i];
      ushort4 o; o.x = f2bf(v.x); o.y = f2bf(v.y); o.z = f2bf(v.z); o.w = f2bf(v.w);
      ((ushort4*)xb)[i] = o;
    }
    for (int i = gid; i < 262144; i += 131072) {    // each W: 1024x1024
      float4 v = ((const float4*)Wq)[i];
      ushort4 o; o.x = f2bf(v.x); o.y = f2bf(v.y); o.z = f2bf(v.z); o.w = f2bf(v.w);
      ((ushort4*)wqb)[i] = o;
      v = ((const float4*)Wk)[i];
      o.x = f2bf(v.x); o.y = f2bf(v.y); o.z = f2bf(v.z); o.w = f2bf(v.w);
      ((ushort4*)wkb)[i] = o;
      v = ((const float4*)Wv)[i];
      o.x = f2bf(v.x); o.y = f2bf(v.y); o.z = f2bf(v.z); o.w = f2bf(v.w);
      ((ushort4*)wvb)[i] = o;
    }
    post1(&F[F_CVT], tid);
  }

  for (;;) {
    __syncthreads();
    if (tid == 0)
      qs = (int)__hip_atomic_fetch_add(&F[F_C1], 1u, __ATOMIC_RELAXED,
                                       __HIP_MEMORY_SCOPE_AGENT);
    __syncthreads();
    const int it = qs;
    if (it >= N_D1) break;

    if (it < 256) {
      // ---- proj: Q = x Wq^T (w=0) / K = x Wk^T (w=1) ----
      gate1(&F[F_CVT], 256, tid);
      const int w = it >> 7, r = it & 127;
      const int rb = r >> 2, n0 = (r & 3) * 256;
      const u16* Bm = w ? wkb : wqb;
      u16* Cm = w ? Kb : Qb;
      gemm_core<u16, 256>(lds, xb + (size_t)rb * 256 * 1024, Bm + (size_t)n0 * 1024,
                          Cm, 16, 1024, 1024, 1024, rb * 256, n0);
      post1(&F[F_PROJ], tid);
    } else if (it < 400) {
      // ---- qkt: 36 lower-tri 256x256 tiles x 4 batches; pops at t~38 when
      //      ALL proj blocks complete simultaneously -> gate pre-satisfied ----
      gate1(&F[F_PROJ], 256, tid);
      const int j = it - 256;
      const int z = j / 36, xt = j % 36;
      int m = 0;
      while ((m + 1) * (m + 2) / 2 <= xt) ++m;
      const int n = xt - m * (m + 1) / 2;
      gemm_core<float, 256>(lds,
          Qb + ((size_t)z * 2048 + m * 256) * 1024,
          Kb + ((size_t)z * 2048 + n * 256) * 1024,
          Sb + (size_t)z * 2048 * 2048,
          16, 1024, 1024, 2048, m * 256, n * 256);
      post1(&F[F_QKT + z * 8 + m], tid);
    } else if (it < 656) {
      // ---- vt: VT_b = Wv x_b^T, fine 128x256 tiles (backfill) ----
      gate1(&F[F_CVT], 256, tid);
      const int j = it - 400;
      const int z = j >> 6, r = j & 63;
      const int m0 = (r >> 3) * 128, n0 = (r & 7) * 256;
      gemm_core<u16, 128>(lds, wvb + (size_t)m0 * 1024,
                          xb + ((size_t)z * 2048) * 1024 + (size_t)n0 * 1024,
                          VTb + (size_t)z * 1024 * 2048,
                          16, 1024, 1024, 2048, m0, n0);
    } else {
      // ---- softmax: (z,m,quarter) = 64 rows; writes bf16 P in place ----
      const int j = it - 656;
      const int qr = j & 3, z = (j >> 2) & 3, m = j >> 4;
      gate1(&F[F_QKT + z * 8 + m], (u32)(m + 1), tid);
      const int iters = m + 1;
      const int wvid = tid >> 6, lane = tid & 63;
      float* S0 = Sb + (size_t)z * 2048 * 2048;
      for (int rr = wvid; rr < 64; rr += 8) {
        const int r = m * 256 + qr * 64 + rr;
        float* row = S0 + (size_t)r * 2048;
        float vals[8][4];
        float mx = -3.4e38f;
#pragma unroll
        for (int it2 = 0; it2 < 8; ++it2)
          if (it2 < iters) {
            const int idx = it2 * 64 + lane;
            float4 v = ((const float4*)row)[idx];
            const int j0 = idx * 4;
            vals[it2][0] = (j0 <= r) ? v.x * 0.03125f : -3.4e38f;
            vals[it2][1] = (j0 + 1 <= r) ? v.y * 0.03125f : -3.4e38f;
            vals[it2][2] = (j0 + 2 <= r) ? v.z * 0.03125f : -3.4e38f;
            vals[it2][3] = (j0 + 3 <= r) ? v.w * 0.03125f : -3.4e38f;
            mx = fmaxf(mx, fmaxf(fmaxf(vals[it2][0], vals[it2][1]),
                                 fmaxf(vals[it2][2], vals[it2][3])));
          }
#pragma unroll
        for (int o = 32; o; o >>= 1) mx = fmaxf(mx, __shfl_xor(mx, o, 64));
        float sum = 0.f;
#pragma unroll
        for (int it2 = 0; it2 < 8; ++it2)
          if (it2 < iters) {
#pragma unroll
            for (int e = 0; e < 4; ++e) {
              const float pp = __expf(vals[it2][e] - mx);
              vals[it2][e] = pp;
              sum += pp;
            }
          }
#pragma unroll
        for (int o = 32; o; o >>= 1) sum += __shfl_xor(sum, o, 64);
        const float rcp = 1.f / sum;
        u16* prow = (u16*)row;
#pragma unroll
        for (int it2 = 0; it2 < 8; ++it2)
          if (it2 < iters) {
            ushort4 o4;
            o4.x = f2bf(vals[it2][0] * rcp);
            o4.y = f2bf(vals[it2][1] * rcp);
            o4.z = f2bf(vals[it2][2] * rcp);
            o4.w = f2bf(vals[it2][3] * rcp);
            ((ushort4*)prow)[it2 * 64 + lane] = o4;
          }
      }
    }
  }
}

// pv chunk classes (desc nt): m-tile, k0 (K-tiles), nt, slot (0=out,1=slot1,2=slot2)
__constant__ signed char CPM[16] = {5,5,7,7,7,6,4,4,6,6,3,3,1,2,2,0};
__constant__ signed char CPK[16] = {0,12,0,11,22,0,0,10,10,19,0,8,0,0,6,0};
__constant__ signed char CPN[16] = {12,12,11,11,10,10,10,10,9,9,8,8,8,6,6,4};
__constant__ signed char CPS[16] = {0,1,0,1,2,0,0,1,1,2,0,1,0,0,1,0};

// ============================================================================
// D2: pv(256, no gates) -> red(192, gate per (z,m) pv counters)
// ============================================================================
__global__ __launch_bounds__(512, 2) void pvred_kernel(
    const u16* __restrict__ P, const u16* __restrict__ VTb,
    float* __restrict__ out, float* __restrict__ Sb, u32* __restrict__ F) {
  __shared__ __align__(16) u16 lds[65536];
  __shared__ int qs;
  const int tid = threadIdx.x;

  for (;;) {
    __syncthreads();
    if (tid == 0)
      qs = (int)__hip_atomic_fetch_add(&F[F_C2], 1u, __ATOMIC_RELAXED,
                                       __HIP_MEMORY_SCOPE_AGENT);
    __syncthreads();
    const int it = qs;
    if (it >= N_D2) break;

    if (it < 256) {
      // ---- pv chunk: O_b = P_b VT_b^T; slots carved from Sb's dead half ----
      const int cls = it >> 4, z = (it >> 2) & 3, n = it & 3;
      const int m = CPM[cls], k0 = CPK[cls], ntc = CPN[cls], sl = CPS[cls];
      const u16* Ap = P + (size_t)z * 2048 * 4096 + (size_t)m * 256 * 4096 +
                      (size_t)k0 * 64;
      const u16* Bp = VTb + (size_t)z * 1024 * 2048 + (size_t)n * 256 * 2048 +
                      (size_t)k0 * 64;
      float* Cp;
      int ldc;
      if (sl == 0) { Cp = out + (size_t)z * 2048 * 1024; ldc = 1024; }
      else if (sl == 1) { Cp = Sb + (size_t)z * 2048 * 2048 + 1024; ldc = 2048; }
      else { Cp = Sb + (size_t)z * 2048 * 2048 + 1024 - (size_t)1536 * 2048; ldc = 2048; }
      gemm_core<float, 256>(lds, Ap, Bp, Cp, ntc, 4096, 2048, ldc, m * 256, n * 256);
      post1(&F[F_PVC + z * 8 + m], tid);
    } else {
      // ---- reduce: out += slot1 (+slot2 for m>=6), fixed order ----
      const int j = it - 256;
      const int m = 2 + (j >> 5), z = (j >> 3) & 3, s = j & 7;
      const u32 tgt = (m >= 6) ? 12u : 8u;
      gate1(&F[F_PVC + z * 8 + m], tgt, tid);
      float* ob = out + (size_t)z * 2048 * 1024;
      const float* s1 = Sb + (size_t)z * 2048 * 2048 + 1024;
      const float* s2 = s1 - (size_t)1536 * 2048;
      const int r0 = m * 256 + s * 32;
      for (int k = tid; k < 32 * 256; k += 512) {   // 32 rows x 256 float4
        const int rr = r0 + (k >> 8), cc = k & 255;
        float4 o = ((float4*)(ob + (size_t)rr * 1024))[cc];
        float4 a = ((const float4*)(s1 + (size_t)rr * 2048))[cc];
        o.x += a.x; o.y += a.y; o.z += a.z; o.w += a.w;
        if (m >= 6) {
          float4 b = ((const float4*)(s2 + (size_t)rr * 2048))[cc];
          o.x += b.x; o.y += b.y; o.z += b.z; o.w += b.w;
        }
        ((float4*)(ob + (size_t)rr * 1024))[cc] = o;
      }
    }
  }
}

extern "C" void kernel_launch(void* const* d_in, const int* in_sizes, int n_in,
                              void* d_out, int out_size, void* d_ws, size_t ws_size,
                              hipStream_t stream) {
  const float* x  = (const float*)d_in[0];
  const float* Wq = (const float*)d_in[1];
  const float* Wk = (const float*)d_in[2];
  const float* Wv = (const float*)d_in[3];
  float* out = (float*)d_out;

  char* ws = (char*)d_ws;
  u16* xb   = (u16*)(ws);                        // 16 MB  x bf16 [8192][1024]
  u16* wqb  = (u16*)(ws + (16ul << 20));         //  2 MB
  u16* wkb  = (u16*)(ws + (18ul << 20));         //  2 MB
  u16* wvb  = (u16*)(ws + (20ul << 20));         //  2 MB
  u16* Qb   = (u16*)(ws + (22ul << 20));         // 16 MB  Q bf16 [4][2048][1024]
  u16* Kb   = (u16*)(ws + (38ul << 20));         // 16 MB  K bf16
  u16* VTb  = (u16*)(ws + (54ul << 20));         // 16 MB  V^T bf16 [4][1024][2048]
  float* Sb = (float*)(ws + (70ul << 20));       // 64 MB  scores fp32; P bf16 in
                                                 //        lower-half cols; dead upper
                                                 //        half hosts pv slot1/slot2
  size_t foff = (ws_size >= (134ul << 20) + 4096) ? (134ul << 20)
                                                  : ((ws_size - 4096) & ~(size_t)255);
  u32* F = (u32*)(ws + foff);

  hipMemsetAsync(F, 0, 512, stream);

  fwd_kernel<<<256, 512, 0, stream>>>(x, Wq, Wk, Wv, xb, wqb, wkb, wvb,
                                      Qb, Kb, VTb, Sb, F);

  pvred_kernel<<<256, 512, 0, stream>>>((const u16*)Sb, VTb, out, Sb, F);
}

// Round 8
// 165.188 us; speedup vs baseline: 2.4820x; 2.0608x over previous
//
#include <hip/hip_runtime.h>

typedef unsigned short u16;
typedef __bf16 bf16x8 __attribute__((ext_vector_type(8)));
typedef float f32x4 __attribute__((ext_vector_type(4)));

#define AS1 __attribute__((address_space(1)))
#define AS3 __attribute__((address_space(3)))

// ---- fp32 -> bf16 (RNE) ----
__device__ inline u16 f2bf(float f) {
  union { float f; unsigned u; } a; a.f = f;
  unsigned u = a.u;
  return (u16)((u + 0x7fffu + ((u >> 16) & 1u)) >> 16);
}

// ---- all fp32 -> bf16 converts in one dispatch ----
__global__ __launch_bounds__(256) void cvt_all_kernel(
    const float* __restrict__ x, const float* __restrict__ wq,
    const float* __restrict__ wk, const float* __restrict__ wv,
    u16* __restrict__ xb, u16* __restrict__ wqb,
    u16* __restrict__ wkb, u16* __restrict__ wvb) {
  int bid = blockIdx.x;
  const float* in; u16* out;
  if (bid < 8192) { in = x; out = xb; }
  else if (bid < 9216) { in = wq; out = wqb; bid -= 8192; }
  else if (bid < 10240) { in = wk; out = wkb; bid -= 9216; }
  else { in = wv; out = wvb; bid -= 10240; }
  size_t i = ((size_t)bid * 256 + threadIdx.x) * 4;
  float4 v = *(const float4*)(in + i);
  ushort4 o;
  o.x = f2bf(v.x); o.y = f2bf(v.y); o.z = f2bf(v.z); o.w = f2bf(v.w);
  *(ushort4*)(out + i) = o;
}

// ============================================================================
// 256xBN 8-wave GEMM core, 4-phase dead-region schedule: C = A @ B^T.
//   BN=256: wave tile 128x64, 16 MFMA/phase; BN=128: wave tile 128x32, 8/phase.
//   RAW s_barrier only; counted vmcnt (never drains the prefetch queue).
//   T2 swizzle: 16B slot ^= (row&7) on both staged source and ds_read.
//   (proven correct rounds 6/7; schedule proven fast rounds 3-5)
// ============================================================================
template <typename CT, int BN>
__device__ __forceinline__ void gemm_core(
    u16* __restrict__ lds,
    const u16* __restrict__ A, const u16* __restrict__ B, CT* __restrict__ C,
    int nt, int lda, int ldb, int ldc, int m0, int n0) {
  constexpr int ABUF = 16384;      // 256 rows x 64 u16 per A buffer
  constexpr int BBUF = BN * 64;
  constexpr int BSW = BN / 64;     // B staging sweeps per tile (4 or 2)
  constexpr int NI = BN / 64;      // n-frags per wave

  const int tid = threadIdx.x;
  const int ln = tid & 63, wv = tid >> 6;
  const int wr = wv >> 2, wc = wv & 3;  // 2 x 4 wave grid

  auto sweep = [&](const u16* src, int ld, int t, int s, int base) {
    const int c = s * 512 + tid;
    const int row = c >> 3, slot = c & 7;
    const int col = (slot ^ (row & 7)) * 8;
    __builtin_amdgcn_global_load_lds(
        (const AS1 void*)(src + (size_t)row * ld + (size_t)t * 64 + col),
        (AS3 void*)(&lds[base + c * 8]), 16, 0, 0);
  };

  f32x4 acc[8][NI] = {};

  // prologue: tiles 0 and 1 fully staged
#pragma unroll
  for (int s = 0; s < BSW; ++s) sweep(B, ldb, 0, s, 2 * ABUF);
#pragma unroll
  for (int s = 0; s < 4; ++s) sweep(A, lda, 0, s, 0);
  if (nt > 1) {
#pragma unroll
    for (int s = 0; s < BSW; ++s) sweep(B, ldb, 1, s, 2 * ABUF + BBUF);
#pragma unroll
    for (int s = 0; s < 4; ++s) sweep(A, lda, 1, s, ABUF);
    if constexpr (BSW == 4) asm volatile("s_waitcnt vmcnt(8)" ::: "memory");
    else                    asm volatile("s_waitcnt vmcnt(6)" ::: "memory");
  } else {
    asm volatile("s_waitcnt vmcnt(0)" ::: "memory");
  }
  __builtin_amdgcn_s_barrier();

  for (int t = 0; t < nt; ++t) {
    const int p = t & 1;
    const u16* La = &lds[p * ABUF];
    const u16* Lb = &lds[2 * ABUF + p * BBUF];
    bf16x8 bfr[NI][2];
#pragma unroll
    for (int q = 0; q < 4; ++q) {
      if (q == 0) {
        __builtin_amdgcn_sched_barrier(0);  // pin reads below publishing barrier
#pragma unroll
        for (int ni = 0; ni < NI; ++ni)
#pragma unroll
          for (int ks = 0; ks < 2; ++ks) {
            const int row = wc * (BN / 4) + ni * 16 + (ln & 15);
            const int kc = ks * 4 + (ln >> 4);
            bfr[ni][ks] = *(const bf16x8*)&Lb[row * 64 + ((kc ^ (row & 7)) << 3)];
          }
      }
      bf16x8 afr[2][2];
#pragma unroll
      for (int mi = 0; mi < 2; ++mi)
#pragma unroll
        for (int ks = 0; ks < 2; ++ks) {
          const int row = wr * 128 + (q * 2 + mi) * 16 + (ln & 15);
          const int kc = ks * 4 + (ln >> 4);
          afr[mi][ks] = *(const bf16x8*)&La[row * 64 + ((kc ^ (row & 7)) << 3)];
        }
      // dead-region staging
      if (q == 0)      { if (t >= 1 && t + 1 < nt) { sweep(A, lda, t + 1, 0, (p ^ 1) * ABUF); sweep(A, lda, t + 1, 1, (p ^ 1) * ABUF); } }
      else if (q == 1) { if (t >= 1 && t + 1 < nt) { sweep(A, lda, t + 1, 2, (p ^ 1) * ABUF); sweep(A, lda, t + 1, 3, (p ^ 1) * ABUF); } }
      else if (q == 2) { if (t + 2 < nt) { sweep(B, ldb, t + 2, 0, 2 * ABUF + p * BBUF); if (BSW == 4) sweep(B, ldb, t + 2, 1, 2 * ABUF + p * BBUF); } }
      else             { if (t + 2 < nt) { if (BSW == 4) { sweep(B, ldb, t + 2, 2, 2 * ABUF + p * BBUF); sweep(B, ldb, t + 2, 3, 2 * ABUF + p * BBUF); } else { sweep(B, ldb, t + 2, 1, 2 * ABUF + p * BBUF); } } }

      __builtin_amdgcn_s_barrier();
      __builtin_amdgcn_s_setprio(1);
#pragma unroll
      for (int mi = 0; mi < 2; ++mi)
#pragma unroll
        for (int ni = 0; ni < NI; ++ni)
#pragma unroll
          for (int ks = 0; ks < 2; ++ks)
            acc[q * 2 + mi][ni] = __builtin_amdgcn_mfma_f32_16x16x32_bf16(
                afr[mi][ks], bfr[ni][ks], acc[q * 2 + mi][ni], 0, 0, 0);
      __builtin_amdgcn_s_setprio(0);
      if (q == 3) {
        if (t + 2 < nt) {
          if constexpr (BSW == 4) asm volatile("s_waitcnt vmcnt(4)" ::: "memory");
          else                    asm volatile("s_waitcnt vmcnt(2)" ::: "memory");
        } else if (t + 1 < nt) {
          asm volatile("s_waitcnt vmcnt(0)" ::: "memory");
        }
      }
      __builtin_amdgcn_s_barrier();
    }
  }

  // epilogue: D col = lane&15 (n), row = (lane>>4)*4 + reg (m)
#pragma unroll
  for (int mi = 0; mi < 8; ++mi) {
    const int rbase = m0 + wr * 128 + mi * 16 + (ln >> 4) * 4;
#pragma unroll
    for (int ni = 0; ni < NI; ++ni) {
      const int col = n0 + wc * (BN / 4) + ni * 16 + (ln & 15);
#pragma unroll
      for (int r = 0; r < 4; ++r) {
        const float v = acc[mi][ni][r];
        CT* ptr = &C[(size_t)(rbase + r) * ldc + col];
        if constexpr (sizeof(CT) == 4) *(float*)ptr = v;
        else                           *ptr = f2bf(v);
      }
    }
  }
}

// ---- Q = x Wq^T, K = x Wk^T: 256 blocks of 256x256 (exactly 1 round) ----
__global__ __launch_bounds__(512, 2) void proj_qk_kernel(
    const u16* __restrict__ xb, const u16* __restrict__ wqb,
    const u16* __restrict__ wkb, u16* __restrict__ Qb, u16* __restrict__ Kb) {
  __shared__ __align__(16) u16 lds[65536];
  const int bid = blockIdx.x;
  const int w = bid >> 7, r = bid & 127;
  const int rb = r >> 2, n0 = (r & 3) * 256;
  const u16* B = w ? wkb : wqb;
  u16* C = w ? Kb : Qb;
  gemm_core<u16, 256>(lds, xb + (size_t)rb * 256 * 1024, B + (size_t)n0 * 1024,
                      C, 16, 1024, 1024, 1024, rb * 256, n0);
}

// ---- vtqkt2: 448 blocks packed for 2 clean rounds.
//   bid 0..31:   vt coarse 256x256 (cols 0..511)       ~38us
//   bid 32..319: qkt fine 256x128, lower-tri halves    ~21us
//   bid 320..447: vt fine 128-col tiles (cols 512..1535)
__global__ __launch_bounds__(512, 2) void vtqkt2_kernel(
    const u16* __restrict__ Qb, const u16* __restrict__ Kb, float* __restrict__ Sb,
    const u16* __restrict__ wvb, const u16* __restrict__ xb, u16* __restrict__ VTb) {
  __shared__ __align__(16) u16 lds[65536];
  const int bid = blockIdx.x;
  if (bid < 32) {
    const int z = bid >> 3, m = (bid >> 1) & 3, n = bid & 1;
    gemm_core<u16, 256>(lds, wvb + (size_t)m * 256 * 1024,
                        xb + (size_t)z * 2048 * 1024 + (size_t)n * 256 * 1024,
                        VTb + (size_t)z * 1024 * 2048,
                        16, 1024, 1024, 2048, m * 256, n * 256);
  } else if (bid < 320) {
    const int j = bid - 32;
    const int z = j / 72, r = j % 72;
    int m = 0;
    while ((m + 1) * (m + 2) <= r) ++m;       // cum halves below m = m(m+1)
    const int h = r - m * (m + 1);            // key half-tile 0..2m+1
    gemm_core<float, 128>(lds,
        Qb + ((size_t)z * 2048 + m * 256) * 1024,
        Kb + ((size_t)z * 2048 + h * 128) * 1024,
        Sb + (size_t)z * 2048 * 2048,
        16, 1024, 1024, 2048, m * 256, h * 128);
  } else {
    const int j = bid - 320;                  // 0..127
    const int z = j >> 5, r = j & 31;
    const int m = r >> 3, nf = r & 7;
    const int n0 = 512 + nf * 128;
    gemm_core<u16, 128>(lds, wvb + (size_t)m * 256 * 1024,
                        xb + (size_t)z * 2048 * 1024 + (size_t)n0 * 1024,
                        VTb + (size_t)z * 1024 * 2048,
                        16, 1024, 1024, 2048, m * 256, n0);
  }
}

// ---- smvt: 64 vt fine tiles (cols 1536..2047) + 512 softmax slices ----
__global__ __launch_bounds__(512, 2) void smvt_kernel(
    float* __restrict__ Sb,
    const u16* __restrict__ wvb, const u16* __restrict__ xb, u16* __restrict__ VTb) {
  __shared__ __align__(16) u16 lds[65536];
  const int bid = blockIdx.x;
  const int tid = threadIdx.x;
  if (bid < 64) {
    const int z = bid >> 4, r = bid & 15;
    const int m = r >> 2, nf = 8 + (r & 3);
    const int n0 = 512 + nf * 128;
    gemm_core<u16, 128>(lds, wvb + (size_t)m * 256 * 1024,
                        xb + (size_t)z * 2048 * 1024 + (size_t)n0 * 1024,
                        VTb + (size_t)z * 1024 * 2048,
                        16, 1024, 1024, 2048, m * 256, n0);
    return;
  }
  // softmax: 16 rows per block; desc-m so long rows start first
  const int j = bid - 64;
  const int m = 7 - (j >> 6), z = (j >> 4) & 3, s = j & 15;
  const int iters = m + 1;
  const int wvid = tid >> 6, lane = tid & 63;
  float* S0 = Sb + (size_t)z * 2048 * 2048;
  for (int rr = wvid; rr < 16; rr += 8) {
    const int r = m * 256 + s * 16 + rr;
    float* row = S0 + (size_t)r * 2048;
    float vals[8][4];
    float mx = -3.4e38f;
#pragma unroll
    for (int it2 = 0; it2 < 8; ++it2)
      if (it2 < iters) {
        const int idx = it2 * 64 + lane;
        float4 v = ((const float4*)row)[idx];
        const int j0 = idx * 4;
        vals[it2][0] = (j0 <= r) ? v.x * 0.03125f : -3.4e38f;
        vals[it2][1] = (j0 + 1 <= r) ? v.y * 0.03125f : -3.4e38f;
        vals[it2][2] = (j0 + 2 <= r) ? v.z * 0.03125f : -3.4e38f;
        vals[it2][3] = (j0 + 3 <= r) ? v.w * 0.03125f : -3.4e38f;
        mx = fmaxf(mx, fmaxf(fmaxf(vals[it2][0], vals[it2][1]),
                             fmaxf(vals[it2][2], vals[it2][3])));
      }
#pragma unroll
    for (int o = 32; o; o >>= 1) mx = fmaxf(mx, __shfl_xor(mx, o, 64));
    float sum = 0.f;
#pragma unroll
    for (int it2 = 0; it2 < 8; ++it2)
      if (it2 < iters) {
#pragma unroll
        for (int e = 0; e < 4; ++e) {
          const float pp = __expf(vals[it2][e] - mx);
          vals[it2][e] = pp;
          sum += pp;
        }
      }
#pragma unroll
    for (int o = 32; o; o >>= 1) sum += __shfl_xor(sum, o, 64);
    const float rcp = 1.f / sum;
    u16* prow = (u16*)row;
#pragma unroll
    for (int it2 = 0; it2 < 8; ++it2)
      if (it2 < iters) {
        ushort4 o4;
        o4.x = f2bf(vals[it2][0] * rcp);
        o4.y = f2bf(vals[it2][1] * rcp);
        o4.z = f2bf(vals[it2][2] * rcp);
        o4.w = f2bf(vals[it2][3] * rcp);
        ((ushort4*)prow)[it2 * 64 + lane] = o4;
      }
  }
}

// pv chunk classes (desc nt): m-tile, k0 (K-tiles), nt, slot (0=out,1=slot1,2=slot2)
__constant__ signed char CPM[16] = {5,5,7,7,7,6,4,4,6,6,3,3,1,2,2,0};
__constant__ signed char CPK[16] = {0,12,0,11,22,0,0,10,10,19,0,8,0,0,6,0};
__constant__ signed char CPN[16] = {12,12,11,11,10,10,10,10,9,9,8,8,8,6,6,4};
__constant__ signed char CPS[16] = {0,1,0,1,2,0,0,1,1,2,0,1,0,0,1,0};

// ---- O_b = P_b VT_b^T (fp32); no atomics; slots carved from Sb's dead region ----
__global__ __launch_bounds__(512, 2) void pv_kernel(
    const u16* __restrict__ P, const u16* __restrict__ VTb,
    float* __restrict__ out, float* __restrict__ Sb) {
  __shared__ __align__(16) u16 lds[65536];
  const int cls = blockIdx.x, n = blockIdx.y;
  const size_t z = blockIdx.z;
  const int m = CPM[cls], k0 = CPK[cls], ntc = CPN[cls], sl = CPS[cls];
  const u16* Ap = P + z * 2048 * 4096 + (size_t)m * 256 * 4096 + (size_t)k0 * 64;
  const u16* Bp = VTb + z * 1024 * 2048 + (size_t)n * 256 * 2048 + (size_t)k0 * 64;
  float* Cp;
  int ldc;
  if (sl == 0) { Cp = out + z * 2048 * 1024; ldc = 1024; }
  else if (sl == 1) { Cp = Sb + z * 2048 * 2048 + 1024; ldc = 2048; }
  else { Cp = Sb + z * 2048 * 2048 + 1024 - (size_t)1536 * 2048; ldc = 2048; }
  gemm_core<float, 256>(lds, Ap, Bp, Cp, ntc, 4096, 2048, ldc, m * 256, n * 256);
}

// ---- out += slot1 (+slot2 for m>=6), fixed order -> deterministic ----
__global__ __launch_bounds__(256) void reduce_kernel(float* __restrict__ out,
                                                     const float* __restrict__ Sb) {
  const int j = blockIdx.x;
  const int m = 2 + (j >> 5), z = (j >> 3) & 3, s = j & 7;
  float* ob = out + (size_t)z * 2048 * 1024;
  const float* s1 = Sb + (size_t)z * 2048 * 2048 + 1024;
  const float* s2 = s1 - (size_t)1536 * 2048;
  const int r0 = m * 256 + s * 32;
  for (int k = threadIdx.x; k < 32 * 256; k += 256) {   // 32 rows x 256 float4
    const int rr = r0 + (k >> 8), cc = k & 255;
    float4 o = ((float4*)(ob + (size_t)rr * 1024))[cc];
    float4 a = ((const float4*)(s1 + (size_t)rr * 2048))[cc];
    o.x += a.x; o.y += a.y; o.z += a.z; o.w += a.w;
    if (m >= 6) {
      float4 b = ((const float4*)(s2 + (size_t)rr * 2048))[cc];
      o.x += b.x; o.y += b.y; o.z += b.z; o.w += b.w;
    }
    ((float4*)(ob + (size_t)rr * 1024))[cc] = o;
  }
}

extern "C" void kernel_launch(void* const* d_in, const int* in_sizes, int n_in,
                              void* d_out, int out_size, void* d_ws, size_t ws_size,
                              hipStream_t stream) {
  const float* x  = (const float*)d_in[0];
  const float* Wq = (const float*)d_in[1];
  const float* Wk = (const float*)d_in[2];
  const float* Wv = (const float*)d_in[3];
  float* out = (float*)d_out;

  char* ws = (char*)d_ws;
  u16* xb   = (u16*)(ws);                        // 16 MB  x bf16 [8192][1024]
  u16* wqb  = (u16*)(ws + (16ul << 20));         //  2 MB
  u16* wkb  = (u16*)(ws + (18ul << 20));         //  2 MB
  u16* wvb  = (u16*)(ws + (20ul << 20));         //  2 MB
  u16* Qb   = (u16*)(ws + (22ul << 20));         // 16 MB  Q bf16 [4][2048][1024]
  u16* Kb   = (u16*)(ws + (38ul << 20));         // 16 MB  K bf16
  u16* VTb  = (u16*)(ws + (54ul << 20));         // 16 MB  V^T bf16 [4][1024][2048]
  float* Sb = (float*)(ws + (70ul << 20));       // 64 MB  scores fp32; P bf16 in
                                                 //        low cols; dead upper region
                                                 //        hosts pv slot1/slot2

  cvt_all_kernel<<<11264, 256, 0, stream>>>(x, Wq, Wk, Wv, xb, wqb, wkb, wvb);

  proj_qk_kernel<<<256, 512, 0, stream>>>(xb, wqb, wkb, Qb, Kb);

  vtqkt2_kernel<<<448, 512, 0, stream>>>(Qb, Kb, Sb, wvb, xb, VTb);

  smvt_kernel<<<576, 512, 0, stream>>>(Sb, wvb, xb, VTb);

  pv_kernel<<<dim3(16, 4, 4), 512, 0, stream>>>((const u16*)Sb, VTb, out, Sb);

  reduce_kernel<<<192, 256, 0, stream>>>(out, Sb);
}